// Round 24
// baseline (242.679 us; speedup 1.0000x reference)
//
#include <hip/hip_runtime.h>
#include <math.h>

#define SRC_LEN  1024
#define BSZ      64
#define CDIM     1024
#define ADIM     1024
#define KDIM     1024
#define MROWS    (SRC_LEN * BSZ)
#define NEG_MASK -1000000.0f

// tiled fp16 layout (256-row tiles): tile = 256 rows x 64 cols,
//   fr = row>>4 (0..15), lr = row&15, cb = col>>3 (0..7), e = col&7
//   hw = fr*1024 + cb*128 + lr*8 + e       (tile = 16384 hw = 32 KB)
// At rows are B-MAJOR: m' = b*1024 + s. enc uses 128-row HALF-tiles:
// half h = rows [h*128,(h+1)*128) = contiguous 8192-hw half of tile h>>1.
#define THW256 16384

typedef _Float16 f16x8 __attribute__((ext_vector_type(8)));
typedef _Float16 f16x4 __attribute__((ext_vector_type(4)));
typedef float    f32x4 __attribute__((ext_vector_type(4)));

__device__ __forceinline__ float fast_tanh(float x) {
    float e = __expf(2.0f * x);
    return 1.0f - 2.0f / (e + 1.0f);
}

// async global(16B) -> LDS, per-lane global src, wave-uniform LDS base
__device__ __forceinline__ void gload16(const _Float16* g, _Float16* l) {
    __builtin_amdgcn_global_load_lds(
        (const __attribute__((address_space(1))) unsigned int*)g,
        (__attribute__((address_space(3))) unsigned int*)l, 16, 0, 0);
}

__device__ __forceinline__ f16x8 frag(const _Float16* buf, int fr, int ks,
                                      int g, int lc) {
    return *reinterpret_cast<const f16x8*>(
        &buf[fr * 1024 + ks * 512 + g * 128 + lc * 8]);
}

__device__ __forceinline__ f16x8 cvt8(float4 x, float4 y) {
    f16x8 o;
    o[0] = (_Float16)x.x; o[1] = (_Float16)x.y;
    o[2] = (_Float16)x.z; o[3] = (_Float16)x.w;
    o[4] = (_Float16)y.x; o[5] = (_Float16)y.y;
    o[6] = (_Float16)y.z; o[7] = (_Float16)y.w;
    return o;
}

// ---------------------------------------------------------------------------
// dec block body: decb[0..63][n0..n0+63] = dsr @ W_dec^T over full K.
// ---------------------------------------------------------------------------
__device__ __forceinline__ void dec_block(const float* __restrict__ A,
                                          const float* __restrict__ W,
                                          float* __restrict__ out,
                                          int n0, int tid,
                                          float (*Asl)[64], float (*Bsl)[64])
{
    const int tx = tid & 15;
    const int ty = tid >> 4;

    float acc[4][4];
#pragma unroll
    for (int i = 0; i < 4; ++i)
#pragma unroll
        for (int j = 0; j < 4; ++j) acc[i][j] = 0.f;

    const int lr = tid >> 2;
    const int lk = (tid & 3) * 4;

    for (int kb = 0; kb < KDIM; kb += 16) {
        float4 a4 = *reinterpret_cast<const float4*>(&A[(size_t)lr * KDIM + kb + lk]);
        float4 b4 = *reinterpret_cast<const float4*>(&W[(size_t)(n0 + lr) * KDIM + kb + lk]);
        __syncthreads();
        Asl[lk + 0][lr] = a4.x; Asl[lk + 1][lr] = a4.y;
        Asl[lk + 2][lr] = a4.z; Asl[lk + 3][lr] = a4.w;
        Bsl[lk + 0][lr] = b4.x; Bsl[lk + 1][lr] = b4.y;
        Bsl[lk + 2][lr] = b4.z; Bsl[lk + 3][lr] = b4.w;
        __syncthreads();
#pragma unroll
        for (int k = 0; k < 16; ++k) {
            float4 av = *reinterpret_cast<const float4*>(&Asl[k][ty * 4]);
            float4 bv = *reinterpret_cast<const float4*>(&Bsl[k][tx * 4]);
            float am[4] = {av.x, av.y, av.z, av.w};
            float bn[4] = {bv.x, bv.y, bv.z, bv.w};
#pragma unroll
            for (int i = 0; i < 4; ++i)
#pragma unroll
                for (int j = 0; j < 4; ++j)
                    acc[i][j] = fmaf(am[i], bn[j], acc[i][j]);
        }
    }
#pragma unroll
    for (int i = 0; i < 4; ++i) {
        int m = ty * 4 + i;
#pragma unroll
        for (int j = 0; j < 4; ++j) {
            int n = n0 + tx * 4 + j;
            out[(size_t)m * ADIM + n] = acc[i][j];
        }
    }
}

// ---------------------------------------------------------------------------
// PREP (fast path): blocks [0,16) dec; [16,16+nW) convert W; [16+nW,+nA)
// convert hids (b-major, skip fully-masked 256-row tiles); next 64 zero
// scoresW + ctx; LAST block builds the HALF-TILE active list (mh = b*8+q,
// active iff len[b] > q*128) into the attn output region.
// ---------------------------------------------------------------------------
__global__ __launch_bounds__(256)
void prep_kernel(const float* __restrict__ dsr, const float* __restrict__ Wdec,
                 float* __restrict__ decb,
                 const float* __restrict__ w_in, _Float16* __restrict__ w_out,
                 const float* __restrict__ a_in, _Float16* __restrict__ a_out,
                 float* __restrict__ zero1,      // scoresW [65536]
                 float* __restrict__ zero2,      // ctx     [65536]
                 const int* __restrict__ lens,
                 int* __restrict__ mlist,        // attn region: [512] + count
                 int nW, int nA)
{
    __shared__ float Asl[16][64];
    __shared__ float Bsl[16][64];

    int bid = blockIdx.x;
    const int t = threadIdx.x;

    if (bid < 16) {
        dec_block(dsr, Wdec, decb, bid * 64, t, Asl, Bsl);
        return;
    }
    bid -= 16;

    if (bid == nW + nA + 64) {     // active half-tile list builder
        if (t == 0) {
            int cnt = 0;
            for (int b = 0; b < BSZ; ++b) {
                int nh = (lens[b] + 127) >> 7;          // 1..8 active halves
                if (nh > 8) nh = 8;
                for (int q = 0; q < nh; ++q) mlist[cnt++] = b * 8 + q;
            }
            mlist[512] = cnt;
        }
        return;
    }

    if (bid >= nW + nA) {   // zero blocks: 2048 floats each
        int zid = bid - nW - nA;              // 0..63
        float* dst = (zid < 32) ? zero1 : zero2;
        int off = (zid & 31) * 2048 + t * 8;
        *reinterpret_cast<float4*>(&dst[off])     = make_float4(0.f, 0.f, 0.f, 0.f);
        *reinterpret_cast<float4*>(&dst[off + 4]) = make_float4(0.f, 0.f, 0.f, 0.f);
        return;
    }

    const bool isA = (bid >= nW);
    const float* in;
    _Float16* out;
    if (!isA) { in = w_in; out = w_out; }
    else      { in = a_in; out = a_out; bid -= nW; }

    const int part = bid & 7;
    const int tile = bid >> 3;           // rt*16 + kt
    const int kt   = tile & 15;
    const int rt   = tile >> 4;

    // Skip fully-masked A tiles (256-row granularity; correct for halves).
    if (isA && lens[rt >> 2] <= (rt & 3) * 256) return;

    const int u  = part * 256 + t;       // 8-elem group 0..2047
    const int fr = u >> 7;
    const int cb = (u >> 4) & 7;
    const int lr = u & 15;

    const size_t drow = (size_t)rt * 256 + fr * 16 + lr;   // dst row
    size_t srow;
    if (isA) {
        const int bcol = (int)(drow >> 10);     // b
        const int s    = (int)(drow & 1023);    // s
        srow = (size_t)s * BSZ + bcol;
    } else {
        srow = drow;
    }
    const int col = kt * 64 + cb * 8;

    float4 x = *reinterpret_cast<const float4*>(&in[srow * KDIM + col]);
    float4 y = *reinterpret_cast<const float4*>(&in[srow * KDIM + col + 4]);
    *reinterpret_cast<f16x8*>(&out[(size_t)tile * THW256 + (size_t)u * 8]) = cvt8(x, y);
}

// ---------------------------------------------------------------------------
// Standalone dec (fallback path)
// ---------------------------------------------------------------------------
__global__ __launch_bounds__(256)
void dec_full_kernel(const float* __restrict__ A, const float* __restrict__ W,
                     float* __restrict__ out)
{
    __shared__ float Asl[16][64];
    __shared__ float Bsl[16][64];
    dec_block(A, W, out, blockIdx.x * 64, threadIdx.x, Asl, Bsl);
}

// ---------------------------------------------------------------------------
// fp32 -> fp16 linear (fallback path W conversion)
// ---------------------------------------------------------------------------
__global__ __launch_bounds__(256)
void convert8_kernel(const float* __restrict__ in, _Float16* __restrict__ out)
{
    size_t i = ((size_t)blockIdx.x * 256 + threadIdx.x) * 8;
    float4 x = *reinterpret_cast<const float4*>(in + i);
    float4 y = *reinterpret_cast<const float4*>(in + i + 4);
    *reinterpret_cast<f16x8*>(out + i) = cvt8(x, y);
}

// ---------------------------------------------------------------------------
// FAST PATH: 128x256 tile (BM=128 halved for makespan granularity), BK=64,
// 8 waves (2Mx4N), wave tile 64x64, 2 phases/K-tile (R8 discipline):
// ph0 {read ks=0 frags || stage A(kt+1), 2 gloads} bar lgkm 16MFMA bar
// ph1 {read ks=1 frags || stage B(kt+1), 4 gloads} bar lgkm 16MFMA
//     vmcnt(0) bar.
// COMPACTED dispatch over active HALF-tiles in mlist; 4 nbt-sharers of one
// mh at positions j, j+8, j+16, j+24 of a 32-chunk (same XCD).
// ---------------------------------------------------------------------------
__global__ __launch_bounds__(512, 1)
void enc_score_256(const _Float16* __restrict__ At,   // b-major tiles
                   const _Float16* __restrict__ Bt,   // [4*16] tiles
                   const float* __restrict__ decb,    // [64][1024]
                   const float* __restrict__ be,      // b_enc
                   const float* __restrict__ bd,      // b_dec
                   const float* __restrict__ v,       // [1024]
                   const int* __restrict__ mlist,     // [512]+count (attn region)
                   float* __restrict__ scores)        // ws [65536] b-major
{
    const int bid   = blockIdx.x;
    const int chunk = bid >> 5;
    const int pos   = bid & 31;
    const int j     = pos & 7;
    const int nbt   = pos >> 3;
    const int i     = chunk * 8 + j;

    if (i >= mlist[512]) return;        // beyond active count (uniform)
    const int mh   = mlist[i];          // half-tile id: b*8 + q
    const int bcol = mh >> 3;

    const int m0 = mh * 128, n0 = nbt * 256;
    const int tid  = threadIdx.x;
    const int lane = tid & 63;
    const int wid  = tid >> 6;          // 0..7
    const int wm   = wid >> 2;          // 0..1  (64-row group)
    const int wn   = wid & 3;           // 0..3  (64-col group)
    const int lc   = lane & 15, g = lane >> 4;

    __shared__ __align__(16) _Float16 As[2][8192];     // 32 KB (A half-slices)
    __shared__ __align__(16) _Float16 Bs[2][THW256];   // 64 KB

    f32x4 acc[4][4];
#pragma unroll
    for (int ii = 0; ii < 4; ++ii)
#pragma unroll
        for (int jj = 0; jj < 4; ++jj) acc[ii][jj] = (f32x4){0.f, 0.f, 0.f, 0.f};

    // A half-slice of tile (mh>>1) at kt: contiguous 8192 hw.
    const _Float16* Abase = At + (size_t)((mh >> 1) * 16) * THW256 + (mh & 1) * 8192;
    const _Float16* Bbase = Bt + (size_t)(nbt * 16) * THW256;

    // ---- prologue: stage K-tile 0 (A: 2 gloads/wave, B: 4 gloads/wave) ----
#pragma unroll
    for (int ii = 0; ii < 2; ++ii) {
        int c = wid * 2 + ii;                 // 0..15, 1KB each
        gload16(Abase + c * 512 + lane * 8, &As[0][c * 512]);
    }
#pragma unroll
    for (int ii = 0; ii < 4; ++ii) {
        int c = wid * 4 + ii;                 // 0..31, 1KB each
        gload16(Bbase + c * 512 + lane * 8, &Bs[0][c * 512]);
    }
    asm volatile("s_waitcnt vmcnt(0)" ::: "memory");
    __builtin_amdgcn_s_barrier();
    asm volatile("" ::: "memory");

    for (int kt = 0; kt < 16; ++kt) {
        const int cur = kt & 1;
        const _Float16* Acur = As[cur];
        const _Float16* Bcur = Bs[cur];
        _Float16* Anxt = As[cur ^ 1];
        _Float16* Bnxt = Bs[cur ^ 1];
        const _Float16* Ag = Abase + (size_t)(kt + 1) * THW256;
        const _Float16* Bg = Bbase + (size_t)(kt + 1) * THW256;
        const bool pre = (kt < 15);

        f16x8 af[4], bf[4];

        // ===== phase 0: ks=0, mi 0..3  (+ stage A of kt+1) =====
#pragma unroll
        for (int ni = 0; ni < 4; ++ni) bf[ni] = frag(Bcur, wn * 4 + ni, 0, g, lc);
#pragma unroll
        for (int ii = 0; ii < 4; ++ii) af[ii] = frag(Acur, wm * 4 + ii, 0, g, lc);
        if (pre) {
#pragma unroll
            for (int ii = 0; ii < 2; ++ii) {
                int c = wid * 2 + ii;
                gload16(Ag + c * 512 + lane * 8, Anxt + c * 512);
            }
        }
        __builtin_amdgcn_s_barrier();
        asm volatile("s_waitcnt lgkmcnt(0)" ::: "memory");
        __builtin_amdgcn_sched_barrier(0);
        __builtin_amdgcn_s_setprio(1);
#pragma unroll
        for (int ii = 0; ii < 4; ++ii)
#pragma unroll
            for (int ni = 0; ni < 4; ++ni)
                acc[ii][ni] = __builtin_amdgcn_mfma_f32_16x16x32_f16(
                    af[ii], bf[ni], acc[ii][ni], 0, 0, 0);
        __builtin_amdgcn_s_setprio(0);
        __builtin_amdgcn_s_barrier();

        // ===== phase 1: ks=1, mi 0..3  (+ stage B of kt+1) =====
#pragma unroll
        for (int ni = 0; ni < 4; ++ni) bf[ni] = frag(Bcur, wn * 4 + ni, 1, g, lc);
#pragma unroll
        for (int ii = 0; ii < 4; ++ii) af[ii] = frag(Acur, wm * 4 + ii, 1, g, lc);
        if (pre) {
#pragma unroll
            for (int ii = 0; ii < 4; ++ii) {
                int c = wid * 4 + ii;
                gload16(Bg + c * 512 + lane * 8, Bnxt + c * 512);
            }
        }
        __builtin_amdgcn_s_barrier();
        asm volatile("s_waitcnt lgkmcnt(0)" ::: "memory");
        __builtin_amdgcn_sched_barrier(0);
        __builtin_amdgcn_s_setprio(1);
#pragma unroll
        for (int ii = 0; ii < 4; ++ii)
#pragma unroll
            for (int ni = 0; ni < 4; ++ni)
                acc[ii][ni] = __builtin_amdgcn_mfma_f32_16x16x32_f16(
                    af[ii], bf[ni], acc[ii][ni], 0, 0, 0);
        __builtin_amdgcn_s_setprio(0);
        if (pre) asm volatile("s_waitcnt vmcnt(0)" ::: "memory");
        __builtin_amdgcn_s_barrier();
        asm volatile("" ::: "memory");
    }

    // ---- fused epilogue: tanh + v-dot + reduce (single b per tile) ----
    __syncthreads();

    float psum[4][4];
#pragma unroll
    for (int mi = 0; mi < 4; ++mi)
#pragma unroll
        for (int r = 0; r < 4; ++r) psum[mi][r] = 0.f;

#pragma unroll
    for (int mi = 0; mi < 4; ++mi) {
#pragma unroll
        for (int ni = 0; ni < 4; ++ni) {
            int n = n0 + wn * 64 + ni * 16 + lc;
            float vn = v[n];
            float bb = be[n] + bd[n] + decb[(size_t)bcol * ADIM + n];
#pragma unroll
            for (int r = 0; r < 4; ++r) {
                float x = acc[mi][ni][r] + bb;
                psum[mi][r] = fmaf(fast_tanh(x), vn, psum[mi][r]);
            }
        }
    }
#pragma unroll
    for (int mi = 0; mi < 4; ++mi)
#pragma unroll
        for (int r = 0; r < 4; ++r) {
            float s = psum[mi][r];
            s += __shfl_xor(s, 1);
            s += __shfl_xor(s, 2);
            s += __shfl_xor(s, 4);
            s += __shfl_xor(s, 8);
            psum[mi][r] = s;
        }

    float* red = reinterpret_cast<float*>(&As[0][0]);   // [128][4] = 2 KB
    if (lc == 0) {
#pragma unroll
        for (int mi = 0; mi < 4; ++mi)
#pragma unroll
            for (int r = 0; r < 4; ++r) {
                int row = wm * 64 + mi * 16 + g * 4 + r;
                red[row * 4 + wn] = psum[mi][r];
            }
    }
    __syncthreads();
    if (tid < 128)
        atomicAdd(&scores[m0 + tid],
                  red[tid * 4] + red[tid * 4 + 1] + red[tid * 4 + 2] + red[tid * 4 + 3]);
}

// ---------------------------------------------------------------------------
// FALLBACK (ws too small): reg-staged fp32-A 128x128 version (orig layouts).
// ---------------------------------------------------------------------------
__global__ __launch_bounds__(256)
void enc_score_fallback(const float* __restrict__ A,
                        const _Float16* __restrict__ Bw,
                        const float* __restrict__ decb,
                        const float* __restrict__ be,
                        const float* __restrict__ bd,
                        const float* __restrict__ v,
                        float* __restrict__ scores)
{
    const int bid = blockIdx.x;
    const int nb  = (bid >> 3) & 7;
    const int mb  = (bid & 7) + ((bid >> 6) << 3);
    const int m0 = mb * 128, n0 = nb * 128;
    const int tid  = threadIdx.x;
    const int lane = tid & 63;
    const int wid  = tid >> 6;
    const int wm   = wid >> 1, wn = wid & 1;
    const int lc   = lane & 15, g = lane >> 4;

    __shared__ __align__(16) _Float16 As[128 * 64];
    __shared__ __align__(16) _Float16 Bs[128 * 64];

    const int srow = tid >> 1;
    const int scol = (tid & 1) * 32;
    const int sw   = (srow & 7) << 3;

    f32x4 acc[4][4];
#pragma unroll
    for (int i = 0; i < 4; ++i)
#pragma unroll
        for (int j = 0; j < 4; ++j) acc[i][j] = (f32x4){0.f, 0.f, 0.f, 0.f};

    const float*    Aptr = A  + (size_t)(m0 + srow) * KDIM + scol;
    const _Float16* Bptr = Bw + (size_t)(n0 + srow) * KDIM + scol;

    float4 aR[8];
    uint4  bR[4];
#pragma unroll
    for (int i = 0; i < 8; ++i) aR[i] = reinterpret_cast<const float4*>(Aptr)[i];
#pragma unroll
    for (int i = 0; i < 4; ++i) bR[i] = reinterpret_cast<const uint4*>(Bptr)[i];

    for (int kb = 0; kb < KDIM; kb += 64) {
        __syncthreads();
#pragma unroll
        for (int w = 0; w < 4; ++w) {
            int hw = (srow * 64 + scol + 8 * w) ^ sw;
            *reinterpret_cast<f16x8*>(&As[hw]) = cvt8(aR[2 * w], aR[2 * w + 1]);
            *reinterpret_cast<uint4*>(&Bs[hw]) = bR[w];
        }
        __syncthreads();
        if (kb + 64 < KDIM) {
#pragma unroll
            for (int i = 0; i < 8; ++i)
                aR[i] = reinterpret_cast<const float4*>(Aptr + kb + 64)[i];
#pragma unroll
            for (int i = 0; i < 4; ++i)
                bR[i] = reinterpret_cast<const uint4*>(Bptr + kb + 64)[i];
        }
#pragma unroll
        for (int ks = 0; ks < 2; ++ks) {
            f16x8 af[4], bf[4];
#pragma unroll
            for (int mi = 0; mi < 4; ++mi) {
                int r  = wm * 64 + mi * 16 + lc;
                int hw = (r * 64 + ks * 32 + g * 8) ^ ((r & 7) << 3);
                af[mi] = *reinterpret_cast<const f16x8*>(&As[hw]);
            }
#pragma unroll
            for (int ni = 0; ni < 4; ++ni) {
                int r  = wn * 64 + ni * 16 + lc;
                int hw = (r * 64 + ks * 32 + g * 8) ^ ((r & 7) << 3);
                bf[ni] = *reinterpret_cast<const f16x8*>(&Bs[hw]);
            }
#pragma unroll
            for (int mi = 0; mi < 4; ++mi)
#pragma unroll
                for (int ni = 0; ni < 4; ++ni)
                    acc[mi][ni] = __builtin_amdgcn_mfma_f32_16x16x32_f16(
                        af[mi], bf[ni], acc[mi][ni], 0, 0, 0);
        }
    }

    __syncthreads();

    float psum[4][4];
#pragma unroll
    for (int mi = 0; mi < 4; ++mi)
#pragma unroll
        for (int r = 0; r < 4; ++r) psum[mi][r] = 0.f;

#pragma unroll
    for (int mi = 0; mi < 4; ++mi) {
#pragma unroll
        for (int ni = 0; ni < 4; ++ni) {
            int n = n0 + wn * 64 + ni * 16 + lc;
            float vn = v[n];
            float bb = be[n] + bd[n];
#pragma unroll
            for (int r = 0; r < 4; ++r) {
                int b = mi * 16 + g * 4 + r;
                float x = acc[mi][ni][r] + decb[(size_t)b * ADIM + n] + bb;
                psum[mi][r] = fmaf(fast_tanh(x), vn, psum[mi][r]);
            }
        }
    }
#pragma unroll
    for (int mi = 0; mi < 4; ++mi)
#pragma unroll
        for (int r = 0; r < 4; ++r) {
            float s = psum[mi][r];
            s += __shfl_xor(s, 1);
            s += __shfl_xor(s, 2);
            s += __shfl_xor(s, 4);
            s += __shfl_xor(s, 8);
            psum[mi][r] = s;
        }

    float* red = reinterpret_cast<float*>(As);
    if (lc == 0) {
#pragma unroll
        for (int mi = 0; mi < 4; ++mi)
#pragma unroll
            for (int r = 0; r < 4; ++r) {
                int row = wm * 64 + mi * 16 + g * 4 + r;
                red[row * 2 + wn] = psum[mi][r];
            }
    }
    __syncthreads();
    if (tid < 128)
        atomicAdd(&scores[m0 + tid], red[tid * 2] + red[tid * 2 + 1]);
}

// ---------------------------------------------------------------------------
// Masked softmax over S per batch column, in place (fallback path).
// ---------------------------------------------------------------------------
__global__ __launch_bounds__(256)
void softmax_kernel(const int* __restrict__ lens, float* __restrict__ attn)
{
    const int b   = blockIdx.x;
    const int tid = threadIdx.x;
    const int len = lens[b];

    float sc[4];
#pragma unroll
    for (int k = 0; k < 4; ++k) {
        int s = k * 256 + tid;
        float x = attn[(size_t)s * BSZ + b];
        sc[k] = (s < len) ? x : NEG_MASK;
    }

    __shared__ float red[8];

    float m = fmaxf(fmaxf(sc[0], sc[1]), fmaxf(sc[2], sc[3]));
#pragma unroll
    for (int off = 32; off > 0; off >>= 1) m = fmaxf(m, __shfl_xor(m, off));
    if ((tid & 63) == 0) red[tid >> 6] = m;
    __syncthreads();
    m = fmaxf(fmaxf(red[0], red[1]), fmaxf(red[2], red[3]));

    float e[4];
    float sum = 0.f;
#pragma unroll
    for (int k = 0; k < 4; ++k) { e[k] = expf(sc[k] - m); sum += e[k]; }
#pragma unroll
    for (int off = 32; off > 0; off >>= 1) sum += __shfl_xor(sum, off);
    __syncthreads();
    if ((tid & 63) == 0) red[4 + (tid >> 6)] = sum;
    __syncthreads();
    float total = red[4] + red[5] + red[6] + red[7];
    float inv = 1.f / total;

#pragma unroll
    for (int k = 0; k < 4; ++k) {
        int s = k * 256 + tid;
        attn[(size_t)s * BSZ + b] = e[k] * inv;
    }
}

// ---------------------------------------------------------------------------
// MERGED softmax+ctx (fast path). grid (8 sc, 64 b).
// scores ws is b-major ([b*1024+s]); At is b-major. Overwrites the attn
// region (which prep used for mlist) completely.
// ---------------------------------------------------------------------------
__global__ __launch_bounds__(256)
void softmax_ctx_kernel(const _Float16* __restrict__ At,
                        const float* __restrict__ scores,  // ws [65536] b-major
                        const int* __restrict__ lens,
                        float* __restrict__ attn,          // out [1024*64]
                        float* __restrict__ ctx)           // out [64*1024]
{
    const int sc  = blockIdx.x;          // 0..7
    const int b   = blockIdx.y;          // 0..63
    const int tid = threadIdx.x;
    const int len = lens[b];

    __shared__ float wl[SRC_LEN];        // 4 KB softmax weights
    __shared__ float red[8];

    float s4[4];
#pragma unroll
    for (int k = 0; k < 4; ++k) {
        int s = k * 256 + tid;
        float x = scores[(size_t)b * SRC_LEN + s];
        s4[k] = (s < len) ? x : NEG_MASK;
    }
    float m = fmaxf(fmaxf(s4[0], s4[1]), fmaxf(s4[2], s4[3]));
#pragma unroll
    for (int off = 32; off > 0; off >>= 1) m = fmaxf(m, __shfl_xor(m, off));
    if ((tid & 63) == 0) red[tid >> 6] = m;
    __syncthreads();
    m = fmaxf(fmaxf(red[0], red[1]), fmaxf(red[2], red[3]));

    float e[4];
    float sum = 0.f;
#pragma unroll
    for (int k = 0; k < 4; ++k) { e[k] = expf(s4[k] - m); sum += e[k]; }
#pragma unroll
    for (int off = 32; off > 0; off >>= 1) sum += __shfl_xor(sum, off);
    __syncthreads();
    if ((tid & 63) == 0) red[4 + (tid >> 6)] = sum;
    __syncthreads();
    float inv = 1.f / (red[4] + red[5] + red[6] + red[7]);

#pragma unroll
    for (int k = 0; k < 4; ++k) wl[k * 256 + tid] = e[k] * inv;
    __syncthreads();

    if (sc == 0) {
#pragma unroll
        for (int k = 0; k < 4; ++k) {
            int s = k * 256 + tid;
            attn[(size_t)s * BSZ + b] = wl[s];
        }
    }

    const int c   = tid * 4;
    const int kt  = c >> 6;
    const int cb  = (c >> 3) & 7;
    const int e2  = c & 7;
    const int sub = cb * 128 + e2;

    float acc[4] = {0.f, 0.f, 0.f, 0.f};
    for (int s = sc * (SRC_LEN / 8); s < (sc + 1) * (SRC_LEN / 8); ++s) {
        float w = wl[s];
        if (w != 0.f) {
            const int mm = b * SRC_LEN + s;     // b-major row
            const int rt = mm >> 8;
            const int fr = (mm >> 4) & 15;
            const int lr = mm & 15;
            f16x4 h = *reinterpret_cast<const f16x4*>(
                &At[(size_t)(rt * 16 + kt) * THW256 + fr * 1024 + sub + lr * 8]);
#pragma unroll
            for (int j = 0; j < 4; ++j) acc[j] = fmaf(w, (float)h[j], acc[j]);
        }
    }
    float* dst = &ctx[(size_t)b * CDIM + c];
#pragma unroll
    for (int j = 0; j < 4; ++j) atomicAdd(dst + j, acc[j]);
}

// ---------------------------------------------------------------------------
// ctx fp32 (fallback path)
// ---------------------------------------------------------------------------
__global__ __launch_bounds__(256)
void ctx_kernel(const float* __restrict__ hids, const float* __restrict__ attn,
                float* __restrict__ ctx)
{
    const int b   = blockIdx.x;
    const int s0  = blockIdx.y * (SRC_LEN / 8);
    const int tid = threadIdx.x;

    float4 acc = make_float4(0.f, 0.f, 0.f, 0.f);
    for (int s = s0; s < s0 + SRC_LEN / 8; ++s) {
        float w = attn[(size_t)s * BSZ + b];
        if (w != 0.f) {
            float4 h = *reinterpret_cast<const float4*>(
                &hids[((size_t)s * BSZ + b) * CDIM + tid * 4]);
            acc.x = fmaf(w, h.x, acc.x);
            acc.y = fmaf(w, h.y, acc.y);
            acc.z = fmaf(w, h.z, acc.z);
            acc.w = fmaf(w, h.w, acc.w);
        }
    }
    float* dst = &ctx[(size_t)b * CDIM + tid * 4];
    atomicAdd(dst + 0, acc.x);
    atomicAdd(dst + 1, acc.y);
    atomicAdd(dst + 2, acc.z);
    atomicAdd(dst + 3, acc.w);
}

// ---------------------------------------------------------------------------
extern "C" void kernel_launch(void* const* d_in, const int* in_sizes, int n_in,
                              void* d_out, int out_size, void* d_ws, size_t ws_size,
                              hipStream_t stream)
{
    const float* dsr   = (const float*)d_in[0];
    const float* hids  = (const float*)d_in[1];
    const int*   lens  = (const int*)  d_in[2];
    const float* W_enc = (const float*)d_in[3];
    const float* b_enc = (const float*)d_in[4];
    const float* W_dec = (const float*)d_in[5];
    const float* b_dec = (const float*)d_in[6];
    const float* v     = (const float*)d_in[7];

    float* out  = (float*)d_out;
    float* ctx  = out;                       // [64*1024]
    float* attn = out + BSZ * CDIM;          // [1024*64]

    const size_t decb_b = (size_t)BSZ * ADIM * 4;     // 256 KB
    const size_t scws_b = (size_t)MROWS * 4;          // 256 KB
    const size_t wf16_b = (size_t)ADIM * KDIM * 2;    // 2 MB
    const size_t af16_b = (size_t)MROWS * KDIM * 2;   // 128 MB

    float*    decb    = (float*)d_ws;
    float*    scoresW = (float*)((char*)d_ws + decb_b);
    _Float16* Wt      = (_Float16*)((char*)d_ws + decb_b + scws_b);
    _Float16* At      = (_Float16*)((char*)d_ws + decb_b + scws_b + wf16_b);

    const bool fast = ws_size >= decb_b + scws_b + wf16_b + af16_b;

    if (fast) {
        int* mlist = (int*)attn;   // attn region reused: prep writes, enc
                                   // reads, softmax_ctx fully overwrites.
        const int nW = (ADIM / 256) * 16 * 8;            // 512
        const int nA = (MROWS / 256) * 16 * 8;           // 32768
        prep_kernel<<<16 + nW + nA + 64 + 1, 256, 0, stream>>>(
            dsr, W_dec, decb, W_enc, Wt, hids, At, scoresW, ctx, lens, mlist, nW, nA);
        enc_score_256<<<2048, 512, 0, stream>>>(At, Wt, decb, b_enc, b_dec, v,
                                                mlist, scoresW);
        softmax_ctx_kernel<<<dim3(8, BSZ), 256, 0, stream>>>(At, scoresW, lens, attn, ctx);
    } else {
        hipMemsetAsync(d_out, 0, (size_t)(BSZ * CDIM + SRC_LEN * BSZ) * sizeof(float), stream);
        dec_full_kernel<<<16, 256, 0, stream>>>(dsr, W_dec, decb);
        convert8_kernel<<<ADIM * KDIM / 8 / 256, 256, 0, stream>>>(W_enc, Wt);
        enc_score_fallback<<<4096, 256, 0, stream>>>(hids, Wt, decb, b_enc, b_dec, v, attn);
        softmax_kernel<<<BSZ, 256, 0, stream>>>(lens, attn);
        ctx_kernel<<<dim3(BSZ, 8), 256, 0, stream>>>(hids, attn, ctx);
    }
}

// Round 25
// 238.738 us; speedup vs baseline: 1.0165x; 1.0165x over previous
//
#include <hip/hip_runtime.h>
#include <math.h>

#define SRC_LEN  1024
#define BSZ      64
#define CDIM     1024
#define ADIM     1024
#define KDIM     1024
#define MROWS    (SRC_LEN * BSZ)
#define NEG_MASK -1000000.0f

// tiled fp16 layout (256-row tiles): tile = 256 rows x 64 cols,
//   fr = row>>4 (0..15), lr = row&15, cb = col>>3 (0..7), e = col&7
//   hw = fr*1024 + cb*128 + lr*8 + e       (tile = 16384 hw = 32 KB)
// At rows are B-MAJOR: m' = b*1024 + s  (per-(b,s-range) tile skip;
// tile mb = b*4 + t covers s in [t*256,(t+1)*256) of one b).
#define THW256 16384

typedef _Float16 f16x8 __attribute__((ext_vector_type(8)));
typedef _Float16 f16x4 __attribute__((ext_vector_type(4)));
typedef float    f32x4 __attribute__((ext_vector_type(4)));

__device__ __forceinline__ float fast_tanh(float x) {
    float e = __expf(2.0f * x);
    return 1.0f - 2.0f / (e + 1.0f);
}

// async global(16B) -> LDS, per-lane global src, wave-uniform LDS base
__device__ __forceinline__ void gload16(const _Float16* g, _Float16* l) {
    __builtin_amdgcn_global_load_lds(
        (const __attribute__((address_space(1))) unsigned int*)g,
        (__attribute__((address_space(3))) unsigned int*)l, 16, 0, 0);
}

__device__ __forceinline__ f16x8 frag(const _Float16* buf, int fr, int ks,
                                      int g, int lc) {
    return *reinterpret_cast<const f16x8*>(
        &buf[fr * 1024 + ks * 512 + g * 128 + lc * 8]);
}

__device__ __forceinline__ f16x8 cvt8(float4 x, float4 y) {
    f16x8 o;
    o[0] = (_Float16)x.x; o[1] = (_Float16)x.y;
    o[2] = (_Float16)x.z; o[3] = (_Float16)x.w;
    o[4] = (_Float16)y.x; o[5] = (_Float16)y.y;
    o[6] = (_Float16)y.z; o[7] = (_Float16)y.w;
    return o;
}

// ---------------------------------------------------------------------------
// dec block body: decb[0..63][n0..n0+63] = dsr @ W_dec^T over full K.
// ---------------------------------------------------------------------------
__device__ __forceinline__ void dec_block(const float* __restrict__ A,
                                          const float* __restrict__ W,
                                          float* __restrict__ out,
                                          int n0, int tid,
                                          float (*Asl)[64], float (*Bsl)[64])
{
    const int tx = tid & 15;
    const int ty = tid >> 4;

    float acc[4][4];
#pragma unroll
    for (int i = 0; i < 4; ++i)
#pragma unroll
        for (int j = 0; j < 4; ++j) acc[i][j] = 0.f;

    const int lr = tid >> 2;
    const int lk = (tid & 3) * 4;

    for (int kb = 0; kb < KDIM; kb += 16) {
        float4 a4 = *reinterpret_cast<const float4*>(&A[(size_t)lr * KDIM + kb + lk]);
        float4 b4 = *reinterpret_cast<const float4*>(&W[(size_t)(n0 + lr) * KDIM + kb + lk]);
        __syncthreads();
        Asl[lk + 0][lr] = a4.x; Asl[lk + 1][lr] = a4.y;
        Asl[lk + 2][lr] = a4.z; Asl[lk + 3][lr] = a4.w;
        Bsl[lk + 0][lr] = b4.x; Bsl[lk + 1][lr] = b4.y;
        Bsl[lk + 2][lr] = b4.z; Bsl[lk + 3][lr] = b4.w;
        __syncthreads();
#pragma unroll
        for (int k = 0; k < 16; ++k) {
            float4 av = *reinterpret_cast<const float4*>(&Asl[k][ty * 4]);
            float4 bv = *reinterpret_cast<const float4*>(&Bsl[k][tx * 4]);
            float am[4] = {av.x, av.y, av.z, av.w};
            float bn[4] = {bv.x, bv.y, bv.z, bv.w};
#pragma unroll
            for (int i = 0; i < 4; ++i)
#pragma unroll
                for (int j = 0; j < 4; ++j)
                    acc[i][j] = fmaf(am[i], bn[j], acc[i][j]);
        }
    }
#pragma unroll
    for (int i = 0; i < 4; ++i) {
        int m = ty * 4 + i;
#pragma unroll
        for (int j = 0; j < 4; ++j) {
            int n = n0 + tx * 4 + j;
            out[(size_t)m * ADIM + n] = acc[i][j];
        }
    }
}

// ---------------------------------------------------------------------------
// PREP (fast path): blocks [0,16) dec; [16,16+nW) convert W (identity rows);
// [16+nW, 16+nW+nA) convert hids with B-MAJOR row permutation, SKIPPING
// tiles whose (b, s-quarter) is fully masked (never read downstream);
// next 64 blocks zero scoresW + ctx; LAST block builds the active-tile list.
// ---------------------------------------------------------------------------
__global__ __launch_bounds__(256)
void prep_kernel(const float* __restrict__ dsr, const float* __restrict__ Wdec,
                 float* __restrict__ decb,
                 const float* __restrict__ w_in, _Float16* __restrict__ w_out,
                 const float* __restrict__ a_in, _Float16* __restrict__ a_out,
                 float* __restrict__ zero1,      // scoresW [65536]
                 float* __restrict__ zero2,      // ctx     [65536]
                 const int* __restrict__ lens,
                 int* __restrict__ mlist,        // attn region: [256] + count
                 int nW, int nA)
{
    __shared__ float Asl[16][64];
    __shared__ float Bsl[16][64];

    int bid = blockIdx.x;
    const int t = threadIdx.x;

    if (bid < 16) {
        dec_block(dsr, Wdec, decb, bid * 64, t, Asl, Bsl);
        return;
    }
    bid -= 16;

    if (bid == nW + nA + 64) {     // active-tile list builder (single block)
        if (t == 0) {
            int cnt = 0;
            for (int b = 0; b < BSZ; ++b) {
                int nt = (lens[b] + 255) >> 8;          // 1..4 active quarters
                for (int q = 0; q < nt; ++q) mlist[cnt++] = b * 4 + q;
            }
            mlist[256] = cnt;
        }
        return;
    }

    if (bid >= nW + nA) {   // zero blocks: 2048 floats each
        int zid = bid - nW - nA;              // 0..63
        float* dst = (zid < 32) ? zero1 : zero2;
        int off = (zid & 31) * 2048 + t * 8;
        *reinterpret_cast<float4*>(&dst[off])     = make_float4(0.f, 0.f, 0.f, 0.f);
        *reinterpret_cast<float4*>(&dst[off + 4]) = make_float4(0.f, 0.f, 0.f, 0.f);
        return;
    }

    const bool isA = (bid >= nW);
    const float* in;
    _Float16* out;
    if (!isA) { in = w_in; out = w_out; }
    else      { in = a_in; out = a_out; bid -= nW; }

    const int part = bid & 7;
    const int tile = bid >> 3;           // rt*16 + kt
    const int kt   = tile & 15;
    const int rt   = tile >> 4;

    // Skip fully-masked A tiles: rt == mb = b*4 + quarter (b-major layout);
    // masked At regions are never read by enc (tile skipped) or softmax_ctx
    // (w == 0 there). Uniform predicate per block.
    if (isA && lens[rt >> 2] <= (rt & 3) * 256) return;

    const int u  = part * 256 + t;       // 8-elem group 0..2047
    const int fr = u >> 7;
    const int cb = (u >> 4) & 7;
    const int lr = u & 15;

    const size_t drow = (size_t)rt * 256 + fr * 16 + lr;   // dst row
    size_t srow;
    if (isA) {
        const int bcol = (int)(drow >> 10);     // b
        const int s    = (int)(drow & 1023);    // s
        srow = (size_t)s * BSZ + bcol;
    } else {
        srow = drow;
    }
    const int col = kt * 64 + cb * 8;

    float4 x = *reinterpret_cast<const float4*>(&in[srow * KDIM + col]);
    float4 y = *reinterpret_cast<const float4*>(&in[srow * KDIM + col + 4]);
    *reinterpret_cast<f16x8*>(&out[(size_t)tile * THW256 + (size_t)u * 8]) = cvt8(x, y);
}

// ---------------------------------------------------------------------------
// Standalone dec (fallback path)
// ---------------------------------------------------------------------------
__global__ __launch_bounds__(256)
void dec_full_kernel(const float* __restrict__ A, const float* __restrict__ W,
                     float* __restrict__ out)
{
    __shared__ float Asl[16][64];
    __shared__ float Bsl[16][64];
    dec_block(A, W, out, blockIdx.x * 64, threadIdx.x, Asl, Bsl);
}

// ---------------------------------------------------------------------------
// fp32 -> fp16 linear (fallback path W conversion)
// ---------------------------------------------------------------------------
__global__ __launch_bounds__(256)
void convert8_kernel(const float* __restrict__ in, _Float16* __restrict__ out)
{
    size_t i = ((size_t)blockIdx.x * 256 + threadIdx.x) * 8;
    float4 x = *reinterpret_cast<const float4*>(in + i);
    float4 y = *reinterpret_cast<const float4*>(in + i + 4);
    *reinterpret_cast<f16x8*>(out + i) = cvt8(x, y);
}

// ---------------------------------------------------------------------------
// FAST PATH: 256x256 tile, BK=64, 8 waves (R16 schedule, 3 phases/K-tile).
// COMPACTED dispatch (R22): active tiles dense in mlist; 4 nbt-sharers of
// each mb on one XCD (positions j, j+8, j+16, j+24 of a 32-chunk).
// ---------------------------------------------------------------------------
__global__ __launch_bounds__(512, 1)
void enc_score_256(const _Float16* __restrict__ At,   // [256*16] tiles, b-major
                   const _Float16* __restrict__ Bt,   // [4*16] tiles
                   const float* __restrict__ decb,    // [64][1024] (no bias)
                   const float* __restrict__ be,      // b_enc
                   const float* __restrict__ bd,      // b_dec
                   const float* __restrict__ v,       // [1024]
                   const int* __restrict__ mlist,     // [256]+count (attn region)
                   float* __restrict__ scores)        // ws [65536] b-major
{
    const int bid   = blockIdx.x;
    const int chunk = bid >> 5;
    const int pos   = bid & 31;
    const int j     = pos & 7;
    const int nbt   = pos >> 3;
    const int i     = chunk * 8 + j;

    if (i >= mlist[256]) return;        // beyond active count (uniform)
    const int mb   = mlist[i];
    const int bcol = mb >> 2;

    const int m0 = mb * 256, n0 = nbt * 256;
    const int tid  = threadIdx.x;
    const int lane = tid & 63;
    const int wid  = tid >> 6;          // 0..7
    const int wm   = wid >> 2;          // 0..1
    const int wn   = wid & 3;           // 0..3
    const int lc   = lane & 15, g = lane >> 4;

    __shared__ __align__(16) _Float16 As[2][THW256];   // 64 KB
    __shared__ __align__(16) _Float16 Bs[2][THW256];   // 64 KB

    f32x4 acc[8][4];
#pragma unroll
    for (int ii = 0; ii < 8; ++ii)
#pragma unroll
        for (int jj = 0; jj < 4; ++jj) acc[ii][jj] = (f32x4){0.f, 0.f, 0.f, 0.f};

    const _Float16* Abase = At + (size_t)(mb * 16) * THW256;
    const _Float16* Bbase = Bt + (size_t)(nbt * 16) * THW256;

    // ---- prologue: stage K-tile 0 into buffer 0 (8 gloads/wave) ----
#pragma unroll
    for (int ii = 0; ii < 4; ++ii) {
        int c = wid * 4 + ii;                 // chunk 0..31, 1KB each
        gload16(Abase + c * 512 + lane * 8, &As[0][c * 512]);
        gload16(Bbase + c * 512 + lane * 8, &Bs[0][c * 512]);
    }
    asm volatile("s_waitcnt vmcnt(0)" ::: "memory");
    __builtin_amdgcn_s_barrier();
    asm volatile("" ::: "memory");

    for (int kt = 0; kt < 16; ++kt) {
        const int cur = kt & 1;
        const _Float16* Acur = As[cur];
        const _Float16* Bcur = Bs[cur];
        _Float16* Anxt = As[cur ^ 1];
        _Float16* Bnxt = Bs[cur ^ 1];
        const _Float16* Ag = Abase + (size_t)(kt + 1) * THW256;
        const _Float16* Bg = Bbase + (size_t)(kt + 1) * THW256;
        const bool pre = (kt < 15);

        f16x8 af[4], bf[4];

        // ===== phase 0: ks=0, mi 0..3  (+ stage A of kt+1) =====
#pragma unroll
        for (int ni = 0; ni < 4; ++ni) bf[ni] = frag(Bcur, wn * 4 + ni, 0, g, lc);
#pragma unroll
        for (int ii = 0; ii < 4; ++ii) af[ii] = frag(Acur, wm * 8 + ii, 0, g, lc);
        if (pre) {
#pragma unroll
            for (int ii = 0; ii < 4; ++ii) {
                int c = wid * 4 + ii;
                gload16(Ag + c * 512 + lane * 8, Anxt + c * 512);
            }
        }
        __builtin_amdgcn_s_barrier();
        asm volatile("s_waitcnt lgkmcnt(0)" ::: "memory");
        __builtin_amdgcn_sched_barrier(0);
        __builtin_amdgcn_s_setprio(1);
#pragma unroll
        for (int ii = 0; ii < 4; ++ii)
#pragma unroll
            for (int ni = 0; ni < 4; ++ni)
                acc[ii][ni] = __builtin_amdgcn_mfma_f32_16x16x32_f16(
                    af[ii], bf[ni], acc[ii][ni], 0, 0, 0);
        __builtin_amdgcn_s_setprio(0);
        __builtin_amdgcn_s_barrier();

        // ===== phase 1: ks=0, mi 4..7  (+ stage B of kt+1) =====
#pragma unroll
        for (int ii = 0; ii < 4; ++ii) af[ii] = frag(Acur, wm * 8 + 4 + ii, 0, g, lc);
        if (pre) {
#pragma unroll
            for (int ii = 0; ii < 4; ++ii) {
                int c = wid * 4 + ii;
                gload16(Bg + c * 512 + lane * 8, Bnxt + c * 512);
            }
        }
        __builtin_amdgcn_s_barrier();
        asm volatile("s_waitcnt lgkmcnt(0)" ::: "memory");
        __builtin_amdgcn_sched_barrier(0);
        __builtin_amdgcn_s_setprio(1);
#pragma unroll
        for (int ii = 0; ii < 4; ++ii)
#pragma unroll
            for (int ni = 0; ni < 4; ++ni)
                acc[4 + ii][ni] = __builtin_amdgcn_mfma_f32_16x16x32_f16(
                    af[ii], bf[ni], acc[4 + ii][ni], 0, 0, 0);
        __builtin_amdgcn_s_setprio(0);
        __builtin_amdgcn_s_barrier();

        // ===== phase 2 (merged 2+3): ks=1, mi 0..7 =====
        f16x8 af8[8];
#pragma unroll
        for (int ni = 0; ni < 4; ++ni) bf[ni] = frag(Bcur, wn * 4 + ni, 1, g, lc);
#pragma unroll
        for (int ii = 0; ii < 8; ++ii) af8[ii] = frag(Acur, wm * 8 + ii, 1, g, lc);
        __builtin_amdgcn_s_barrier();
        asm volatile("s_waitcnt lgkmcnt(0)" ::: "memory");
        __builtin_amdgcn_sched_barrier(0);
        __builtin_amdgcn_s_setprio(1);
#pragma unroll
        for (int ii = 0; ii < 8; ++ii)
#pragma unroll
            for (int ni = 0; ni < 4; ++ni)
                acc[ii][ni] = __builtin_amdgcn_mfma_f32_16x16x32_f16(
                    af8[ii], bf[ni], acc[ii][ni], 0, 0, 0);
        __builtin_amdgcn_s_setprio(0);
        if (pre) asm volatile("s_waitcnt vmcnt(0)" ::: "memory");
        __builtin_amdgcn_s_barrier();
        asm volatile("" ::: "memory");
    }

    // ---- fused epilogue: tanh + v-dot + reduce (single b per tile) ----
    __syncthreads();

    float psum[8][4];
#pragma unroll
    for (int mi = 0; mi < 8; ++mi)
#pragma unroll
        for (int r = 0; r < 4; ++r) psum[mi][r] = 0.f;

#pragma unroll
    for (int mi = 0; mi < 8; ++mi) {
#pragma unroll
        for (int ni = 0; ni < 4; ++ni) {
            int n = n0 + wn * 64 + ni * 16 + lc;
            float vn = v[n];
            float bb = be[n] + bd[n] + decb[(size_t)bcol * ADIM + n];
#pragma unroll
            for (int r = 0; r < 4; ++r) {
                float x = acc[mi][ni][r] + bb;
                psum[mi][r] = fmaf(fast_tanh(x), vn, psum[mi][r]);
            }
        }
    }
#pragma unroll
    for (int mi = 0; mi < 8; ++mi)
#pragma unroll
        for (int r = 0; r < 4; ++r) {
            float s = psum[mi][r];
            s += __shfl_xor(s, 1);
            s += __shfl_xor(s, 2);
            s += __shfl_xor(s, 4);
            s += __shfl_xor(s, 8);
            psum[mi][r] = s;
        }

    float* red = reinterpret_cast<float*>(&As[0][0]);   // [256][4]
    if (lc == 0) {
#pragma unroll
        for (int mi = 0; mi < 8; ++mi)
#pragma unroll
            for (int r = 0; r < 4; ++r) {
                int row = wm * 128 + mi * 16 + g * 4 + r;
                red[row * 4 + wn] = psum[mi][r];
            }
    }
    __syncthreads();
    if (tid < 256)
        atomicAdd(&scores[m0 + tid],
                  red[tid * 4] + red[tid * 4 + 1] + red[tid * 4 + 2] + red[tid * 4 + 3]);
}

// ---------------------------------------------------------------------------
// FALLBACK (ws too small): reg-staged fp32-A 128x128 version (orig layouts).
// ---------------------------------------------------------------------------
__global__ __launch_bounds__(256)
void enc_score_fallback(const float* __restrict__ A,
                        const _Float16* __restrict__ Bw,
                        const float* __restrict__ decb,
                        const float* __restrict__ be,
                        const float* __restrict__ bd,
                        const float* __restrict__ v,
                        float* __restrict__ scores)
{
    const int bid = blockIdx.x;
    const int nb  = (bid >> 3) & 7;
    const int mb  = (bid & 7) + ((bid >> 6) << 3);
    const int m0 = mb * 128, n0 = nb * 128;
    const int tid  = threadIdx.x;
    const int lane = tid & 63;
    const int wid  = tid >> 6;
    const int wm   = wid >> 1, wn = wid & 1;
    const int lc   = lane & 15, g = lane >> 4;

    __shared__ __align__(16) _Float16 As[128 * 64];
    __shared__ __align__(16) _Float16 Bs[128 * 64];

    const int srow = tid >> 1;
    const int scol = (tid & 1) * 32;
    const int sw   = (srow & 7) << 3;

    f32x4 acc[4][4];
#pragma unroll
    for (int i = 0; i < 4; ++i)
#pragma unroll
        for (int j = 0; j < 4; ++j) acc[i][j] = (f32x4){0.f, 0.f, 0.f, 0.f};

    const float*    Aptr = A  + (size_t)(m0 + srow) * KDIM + scol;
    const _Float16* Bptr = Bw + (size_t)(n0 + srow) * KDIM + scol;

    float4 aR[8];
    uint4  bR[4];
#pragma unroll
    for (int i = 0; i < 8; ++i) aR[i] = reinterpret_cast<const float4*>(Aptr)[i];
#pragma unroll
    for (int i = 0; i < 4; ++i) bR[i] = reinterpret_cast<const uint4*>(Bptr)[i];

    for (int kb = 0; kb < KDIM; kb += 64) {
        __syncthreads();
#pragma unroll
        for (int w = 0; w < 4; ++w) {
            int hw = (srow * 64 + scol + 8 * w) ^ sw;
            *reinterpret_cast<f16x8*>(&As[hw]) = cvt8(aR[2 * w], aR[2 * w + 1]);
            *reinterpret_cast<uint4*>(&Bs[hw]) = bR[w];
        }
        __syncthreads();
        if (kb + 64 < KDIM) {
#pragma unroll
            for (int i = 0; i < 8; ++i)
                aR[i] = reinterpret_cast<const float4*>(Aptr + kb + 64)[i];
#pragma unroll
            for (int i = 0; i < 4; ++i)
                bR[i] = reinterpret_cast<const uint4*>(Bptr + kb + 64)[i];
        }
#pragma unroll
        for (int ks = 0; ks < 2; ++ks) {
            f16x8 af[4], bf[4];
#pragma unroll
            for (int mi = 0; mi < 4; ++mi) {
                int r  = wm * 64 + mi * 16 + lc;
                int hw = (r * 64 + ks * 32 + g * 8) ^ ((r & 7) << 3);
                af[mi] = *reinterpret_cast<const f16x8*>(&As[hw]);
            }
#pragma unroll
            for (int ni = 0; ni < 4; ++ni) {
                int r  = wn * 64 + ni * 16 + lc;
                int hw = (r * 64 + ks * 32 + g * 8) ^ ((r & 7) << 3);
                bf[ni] = *reinterpret_cast<const f16x8*>(&Bs[hw]);
            }
#pragma unroll
            for (int mi = 0; mi < 4; ++mi)
#pragma unroll
                for (int ni = 0; ni < 4; ++ni)
                    acc[mi][ni] = __builtin_amdgcn_mfma_f32_16x16x32_f16(
                        af[mi], bf[ni], acc[mi][ni], 0, 0, 0);
        }
    }

    __syncthreads();

    float psum[4][4];
#pragma unroll
    for (int mi = 0; mi < 4; ++mi)
#pragma unroll
        for (int r = 0; r < 4; ++r) psum[mi][r] = 0.f;

#pragma unroll
    for (int mi = 0; mi < 4; ++mi) {
#pragma unroll
        for (int ni = 0; ni < 4; ++ni) {
            int n = n0 + wn * 64 + ni * 16 + lc;
            float vn = v[n];
            float bb = be[n] + bd[n];
#pragma unroll
            for (int r = 0; r < 4; ++r) {
                int b = mi * 16 + g * 4 + r;
                float x = acc[mi][ni][r] + decb[(size_t)b * ADIM + n] + bb;
                psum[mi][r] = fmaf(fast_tanh(x), vn, psum[mi][r]);
            }
        }
    }
#pragma unroll
    for (int mi = 0; mi < 4; ++mi)
#pragma unroll
        for (int r = 0; r < 4; ++r) {
            float s = psum[mi][r];
            s += __shfl_xor(s, 1);
            s += __shfl_xor(s, 2);
            s += __shfl_xor(s, 4);
            s += __shfl_xor(s, 8);
            psum[mi][r] = s;
        }

    float* red = reinterpret_cast<float*>(As);
    if (lc == 0) {
#pragma unroll
        for (int mi = 0; mi < 4; ++mi)
#pragma unroll
            for (int r = 0; r < 4; ++r) {
                int row = wm * 64 + mi * 16 + g * 4 + r;
                red[row * 2 + wn] = psum[mi][r];
            }
    }
    __syncthreads();
    if (tid < 128)
        atomicAdd(&scores[m0 + tid], red[tid * 2] + red[tid * 2 + 1]);
}

// ---------------------------------------------------------------------------
// Masked softmax over S per batch column, in place (fallback path).
// ---------------------------------------------------------------------------
__global__ __launch_bounds__(256)
void softmax_kernel(const int* __restrict__ lens, float* __restrict__ attn)
{
    const int b   = blockIdx.x;
    const int tid = threadIdx.x;
    const int len = lens[b];

    float sc[4];
#pragma unroll
    for (int k = 0; k < 4; ++k) {
        int s = k * 256 + tid;
        float x = attn[(size_t)s * BSZ + b];
        sc[k] = (s < len) ? x : NEG_MASK;
    }

    __shared__ float red[8];

    float m = fmaxf(fmaxf(sc[0], sc[1]), fmaxf(sc[2], sc[3]));
#pragma unroll
    for (int off = 32; off > 0; off >>= 1) m = fmaxf(m, __shfl_xor(m, off));
    if ((tid & 63) == 0) red[tid >> 6] = m;
    __syncthreads();
    m = fmaxf(fmaxf(red[0], red[1]), fmaxf(red[2], red[3]));

    float e[4];
    float sum = 0.f;
#pragma unroll
    for (int k = 0; k < 4; ++k) { e[k] = expf(sc[k] - m); sum += e[k]; }
#pragma unroll
    for (int off = 32; off > 0; off >>= 1) sum += __shfl_xor(sum, off);
    __syncthreads();
    if ((tid & 63) == 0) red[4 + (tid >> 6)] = sum;
    __syncthreads();
    float total = red[4] + red[5] + red[6] + red[7];
    float inv = 1.f / total;

#pragma unroll
    for (int k = 0; k < 4; ++k) {
        int s = k * 256 + tid;
        attn[(size_t)s * BSZ + b] = e[k] * inv;
    }
}

// ---------------------------------------------------------------------------
// MERGED softmax+ctx (fast path). grid (8 sc, 64 b).
// scores ws is b-major ([b*1024+s]); At is b-major. Overwrites the attn
// region (which prep used for mlist) completely.
// ---------------------------------------------------------------------------
__global__ __launch_bounds__(256)
void softmax_ctx_kernel(const _Float16* __restrict__ At,
                        const float* __restrict__ scores,  // ws [65536] b-major
                        const int* __restrict__ lens,
                        float* __restrict__ attn,          // out [1024*64]
                        float* __restrict__ ctx)           // out [64*1024]
{
    const int sc  = blockIdx.x;          // 0..7
    const int b   = blockIdx.y;          // 0..63
    const int tid = threadIdx.x;
    const int len = lens[b];

    __shared__ float wl[SRC_LEN];        // 4 KB softmax weights
    __shared__ float red[8];

    float s4[4];
#pragma unroll
    for (int k = 0; k < 4; ++k) {
        int s = k * 256 + tid;
        float x = scores[(size_t)b * SRC_LEN + s];
        s4[k] = (s < len) ? x : NEG_MASK;
    }
    float m = fmaxf(fmaxf(s4[0], s4[1]), fmaxf(s4[2], s4[3]));
#pragma unroll
    for (int off = 32; off > 0; off >>= 1) m = fmaxf(m, __shfl_xor(m, off));
    if ((tid & 63) == 0) red[tid >> 6] = m;
    __syncthreads();
    m = fmaxf(fmaxf(red[0], red[1]), fmaxf(red[2], red[3]));

    float e[4];
    float sum = 0.f;
#pragma unroll
    for (int k = 0; k < 4; ++k) { e[k] = expf(s4[k] - m); sum += e[k]; }
#pragma unroll
    for (int off = 32; off > 0; off >>= 1) sum += __shfl_xor(sum, off);
    __syncthreads();
    if ((tid & 63) == 0) red[4 + (tid >> 6)] = sum;
    __syncthreads();
    float inv = 1.f / (red[4] + red[5] + red[6] + red[7]);

#pragma unroll
    for (int k = 0; k < 4; ++k) wl[k * 256 + tid] = e[k] * inv;
    __syncthreads();

    if (sc == 0) {
#pragma unroll
        for (int k = 0; k < 4; ++k) {
            int s = k * 256 + tid;
            attn[(size_t)s * BSZ + b] = wl[s];
        }
    }

    const int c   = tid * 4;
    const int kt  = c >> 6;
    const int cb  = (c >> 3) & 7;
    const int e2  = c & 7;
    const int sub = cb * 128 + e2;

    float acc[4] = {0.f, 0.f, 0.f, 0.f};
    for (int s = sc * (SRC_LEN / 8); s < (sc + 1) * (SRC_LEN / 8); ++s) {
        float w = wl[s];
        if (w != 0.f) {
            const int mm = b * SRC_LEN + s;     // b-major row
            const int rt = mm >> 8;
            const int fr = (mm >> 4) & 15;
            const int lr = mm & 15;
            f16x4 h = *reinterpret_cast<const f16x4*>(
                &At[(size_t)(rt * 16 + kt) * THW256 + fr * 1024 + sub + lr * 8]);
#pragma unroll
            for (int j = 0; j < 4; ++j) acc[j] = fmaf(w, (float)h[j], acc[j]);
        }
    }
    float* dst = &ctx[(size_t)b * CDIM + c];
#pragma unroll
    for (int j = 0; j < 4; ++j) atomicAdd(dst + j, acc[j]);
}

// ---------------------------------------------------------------------------
// ctx fp32 (fallback path)
// ---------------------------------------------------------------------------
__global__ __launch_bounds__(256)
void ctx_kernel(const float* __restrict__ hids, const float* __restrict__ attn,
                float* __restrict__ ctx)
{
    const int b   = blockIdx.x;
    const int s0  = blockIdx.y * (SRC_LEN / 8);
    const int tid = threadIdx.x;

    float4 acc = make_float4(0.f, 0.f, 0.f, 0.f);
    for (int s = s0; s < s0 + SRC_LEN / 8; ++s) {
        float w = attn[(size_t)s * BSZ + b];
        if (w != 0.f) {
            float4 h = *reinterpret_cast<const float4*>(
                &hids[((size_t)s * BSZ + b) * CDIM + tid * 4]);
            acc.x = fmaf(w, h.x, acc.x);
            acc.y = fmaf(w, h.y, acc.y);
            acc.z = fmaf(w, h.z, acc.z);
            acc.w = fmaf(w, h.w, acc.w);
        }
    }
    float* dst = &ctx[(size_t)b * CDIM + tid * 4];
    atomicAdd(dst + 0, acc.x);
    atomicAdd(dst + 1, acc.y);
    atomicAdd(dst + 2, acc.z);
    atomicAdd(dst + 3, acc.w);
}

// ---------------------------------------------------------------------------
extern "C" void kernel_launch(void* const* d_in, const int* in_sizes, int n_in,
                              void* d_out, int out_size, void* d_ws, size_t ws_size,
                              hipStream_t stream)
{
    const float* dsr   = (const float*)d_in[0];
    const float* hids  = (const float*)d_in[1];
    const int*   lens  = (const int*)  d_in[2];
    const float* W_enc = (const float*)d_in[3];
    const float* b_enc = (const float*)d_in[4];
    const float* W_dec = (const float*)d_in[5];
    const float* b_dec = (const float*)d_in[6];
    const float* v     = (const float*)d_in[7];

    float* out  = (float*)d_out;
    float* ctx  = out;                       // [64*1024]
    float* attn = out + BSZ * CDIM;          // [1024*64]

    const size_t decb_b = (size_t)BSZ * ADIM * 4;     // 256 KB
    const size_t scws_b = (size_t)MROWS * 4;          // 256 KB
    const size_t wf16_b = (size_t)ADIM * KDIM * 2;    // 2 MB
    const size_t af16_b = (size_t)MROWS * KDIM * 2;   // 128 MB

    float*    decb    = (float*)d_ws;
    float*    scoresW = (float*)((char*)d_ws + decb_b);
    _Float16* Wt      = (_Float16*)((char*)d_ws + decb_b + scws_b);
    _Float16* At      = (_Float16*)((char*)d_ws + decb_b + scws_b + wf16_b);

    const bool fast = ws_size >= decb_b + scws_b + wf16_b + af16_b;

    if (fast) {
        int* mlist = (int*)attn;   // attn region reused: prep writes, enc
                                   // reads, softmax_ctx fully overwrites.
        const int nW = (ADIM / 256) * 16 * 8;            // 512
        const int nA = (MROWS / 256) * 16 * 8;           // 32768
        prep_kernel<<<16 + nW + nA + 64 + 1, 256, 0, stream>>>(
            dsr, W_dec, decb, W_enc, Wt, hids, At, scoresW, ctx, lens, mlist, nW, nA);
        enc_score_256<<<1024, 512, 0, stream>>>(At, Wt, decb, b_enc, b_dec, v,
                                                mlist, scoresW);
        softmax_ctx_kernel<<<dim3(8, BSZ), 256, 0, stream>>>(At, scoresW, lens, attn, ctx);
    } else {
        hipMemsetAsync(d_out, 0, (size_t)(BSZ * CDIM + SRC_LEN * BSZ) * sizeof(float), stream);
        dec_full_kernel<<<16, 256, 0, stream>>>(dsr, W_dec, decb);
        convert8_kernel<<<ADIM * KDIM / 8 / 256, 256, 0, stream>>>(W_enc, Wt);
        enc_score_fallback<<<4096, 256, 0, stream>>>(hids, Wt, decb, b_enc, b_dec, v, attn);
        softmax_kernel<<<BSZ, 256, 0, stream>>>(lens, attn);
        ctx_kernel<<<dim3(BSZ, 8), 256, 0, stream>>>(hids, attn, ctx);
    }
}